// Round 1
// baseline (321.264 us; speedup 1.0000x reference)
//
#include <hip/hip_runtime.h>
#include <math.h>

#define BATCH 256
#define D0 256
#define D1 512
#define D2 256
#define D3 128

// fp32 inter-layer activations — replicating numpy's fp32 pipeline.
__device__ float g_xnT0[D0 * BATCH];
__device__ float g_xnT1[D1 * BATCH];
__device__ float g_xnT2[D2 * BATCH];

template <int L> __device__ __forceinline__ float* xnT_ptr() {
    if constexpr (L == 0) return g_xnT0;
    else if constexpr (L == 1) return g_xnT1;
    else return g_xnT2;
}

__device__ __forceinline__ float tanh_f32_cr(float x) {
    return (float)tanh((double)x);
}

__global__ void prep_tanhT(const float* __restrict__ x) {
    int i = threadIdx.x;   // 0..255
    int b = blockIdx.x;    // 0..255
    g_xnT0[i * BATCH + b] = tanh_f32_cr(x[b * D0 + i]);
}

// Numerics (FROZEN — r17 proved it): per-term fp32 ops d=|xn-g|, m=d*s;
// RN32(exp(m)) via fp64 deg-8 Taylor + exact ldexpf (deg-7 flipped the bf16
// argmax by one quantum -> fail). Accumulation = numpy einsum baseline-SSE
// exactly: 4 lanes, unfused mul+add, reversed chain
// acc = p0+(p4+(p8+(p12+acc))), hadd tree (v0+v1)+(v2+v3). 1.95e-2 vs 2e-2.
//
// Falsification ledger: r14/r15 schedule pinning + LU-templating (WIN,
// banked); r16 2x occupancy (neutral — issue-bound); r17 cheaper exp (FAIL
// numerics); r7/r12 accumulation restructure (FAIL numerics); r20 VMEM
// prefetch (regression — scratch spill inside the fenced region, WRITE_SIZE
// 256KB->26MB). r10/r18 were system-level flakes.
//
// r22 (this round): RETRY of the r20 *idea* with a spill-proof
// implementation. Diagnosis: FETCH_SIZE 5.3GB/dispatch = phase-top operand
// loads are L2-misses (~400-600cy via L3); identical pinned streams convoy
// all waves onto the same stall -> the 15% VALU idle. Fix: 2x-unrolled
// software pipeline, static-index double buffers ONLY for the critical-path
// operands (xnv[16] in VGPR; svv[0..3]/wvv[0..3] in SGPR, +8 SGPR). Tails
// stay at the phase top (first use >=1 stage-group away, already covered).
// Every fp op, operand value, and the acc-chain order are bit-identical:
// scheduling-only change, numerics untouched by construction.
// launch_bounds(256,6): spill insurance (r20 lesson) — allows up to ~84
// VGPR before scratch; if alloc lands <=64 occupancy is unchanged.

// One 80-term phase for one SSE lane (20 terms this wave).
// xnv/sv0/wv0: this phase's critical operands (prefetched by caller/previous
// phase). svt/wvt: this phase's tail operands (loaded here). nxnv/nsv0/nwv0:
// prefetch targets for the NEXT phase, issued after the q=0 group.
template <int LU>
__device__ __forceinline__ void sse_phase(
    float& acc,
    const float (&xnv)[16], const float (&sv0)[4], const float (&wv0)[4],
    float (&svt)[12], float (&wvt)[16],
    float (&nxnv)[16], float (&nsv0)[4], float (&nwv0)[4],
    const float* __restrict__ xnT, const float* __restrict__ wr,
    const float* __restrict__ sr, const int b, const int blk, const int nblk)
{
#pragma clang fp contract(off)
    const int ibase = blk / 5;
    const int nibase = nblk / 5;

    // ---- tail operands for THIS phase (first use is q>=1, ~350cy away) ----
#pragma unroll
    for (int ii = 4; ii < 16; ++ii) svt[ii - 4] = sr[ibase + ii];     // uniform s_load
#pragma unroll
    for (int jj = 4; jj < 20; ++jj) wvt[jj - 4] = wr[blk + 4 * jj + LU];
    __builtin_amdgcn_sched_barrier(0);

#pragma unroll
    for (int q = 0; q < 5; ++q) {              // five 16-element SSE groups
        double uu[4], pp[4];
        int ni[4];
        // ---- args + range reduction, 4 chains (ops identical to r8) ----
#pragma unroll
        for (int j = 0; j < 4; ++j) {
            constexpr int Uq[4] = {0, 4, 8, 12};
            const int U = q * 16 + Uq[j];      // compile-time
            const int c = U % 5;               // compile-time
            const int sum = c + LU;            // compile-time
            const int carry = (sum >= 5) ? 1 : 0;
            const int idx = U / 5 + carry;     // compile-time
            const float gv = 0.5f * (float)(sum - 5 * carry) - 1.0f;
            const float xv = xnv[idx];                          // static idx
            const float sv = (idx < 4) ? sv0[idx] : svt[idx - 4]; // static sel
            const float d = fabsf(xv - gv);             // RN32
            const float m = -(d * sv);                  // RN32
            const double tt = (double)m * 1.4426950408889634;
            const double nn = rint(tt);
            ni[j] = (int)nn;
            uu[j] = (tt - nn) * 0.6931471805599453;
        }
        __builtin_amdgcn_sched_barrier(0);
        // ---- pinned 4-wide fp64 Taylor stages (deg-8, FROZEN) ----
#pragma unroll
        for (int j = 0; j < 4; ++j) pp[j] = fma(1.0 / 40320.0, uu[j], 1.0 / 5040.0);
        __builtin_amdgcn_sched_barrier(0);
#pragma unroll
        for (int j = 0; j < 4; ++j) pp[j] = fma(pp[j], uu[j], 1.0 / 720.0);
        __builtin_amdgcn_sched_barrier(0);
#pragma unroll
        for (int j = 0; j < 4; ++j) pp[j] = fma(pp[j], uu[j], 1.0 / 120.0);
        __builtin_amdgcn_sched_barrier(0);
#pragma unroll
        for (int j = 0; j < 4; ++j) pp[j] = fma(pp[j], uu[j], 1.0 / 24.0);
        __builtin_amdgcn_sched_barrier(0);
#pragma unroll
        for (int j = 0; j < 4; ++j) pp[j] = fma(pp[j], uu[j], 1.0 / 6.0);
        __builtin_amdgcn_sched_barrier(0);
#pragma unroll
        for (int j = 0; j < 4; ++j) pp[j] = fma(pp[j], uu[j], 0.5);
        __builtin_amdgcn_sched_barrier(0);
#pragma unroll
        for (int j = 0; j < 4; ++j) pp[j] = fma(pp[j], uu[j], 1.0);
        __builtin_amdgcn_sched_barrier(0);
#pragma unroll
        for (int j = 0; j < 4; ++j) pp[j] = fma(pp[j], uu[j], 1.0);
        __builtin_amdgcn_sched_barrier(0);
        // ---- RN32 + exact 2^n + RN32 product ----
        float p[4];
#pragma unroll
        for (int j = 0; j < 4; ++j) {
            const int n = q * 4 + j;           // compile-time
            const float wv = (n < 4) ? wv0[n] : wvt[n - 4];
            p[j] = ldexpf((float)pp[j], ni[j]) * wv;
        }
        __builtin_amdgcn_sched_barrier(0);
        // ---- reversed chain, order-locked (j=3,2,1,0) ----
        acc = p[3] + acc;
        acc = p[2] + acc;
        acc = p[1] + acc;
        acc = p[0] + acc;

        if (q == 0) {
            // ---- prefetch NEXT phase's critical operands. Issued here
            // (~4 stage-groups, >1200cy before first use); VMEM/SMEM issue
            // only, no VALU-pipe cost. No trailing wall: keeps the q0 acc
            // chain free to interleave with q1 args as in the banked r19. ----
#pragma unroll
            for (int ii = 0; ii < 16; ++ii)
                nxnv[ii] = xnT[(nibase + ii) * BATCH + b];   // coalesced VMEM
#pragma unroll
            for (int ii = 0; ii < 4; ++ii) nsv0[ii] = sr[nibase + ii];
#pragma unroll
            for (int jj = 0; jj < 4; ++jj) nwv0[jj] = wr[nblk + 4 * jj + LU];
        }
    }
}

template <int IN, int LU>
__device__ __forceinline__ float sse_chain(const float* __restrict__ xnT,
                                           const float* __restrict__ wr,
                                           const float* __restrict__ sr,
                                           const int b)
{
#pragma clang fp contract(off)
    constexpr int K = IN * 5;                  // 1280 or 2560: multiple of 160
    float acc = 0.f;

    float xnvA[16], xnvB[16];
    float svA0[4], svB0[4], wvA0[4], wvB0[4];
    float svt[12], wvt[16];

    // ---- prologue: critical operands for phase 0 ----
#pragma unroll
    for (int ii = 0; ii < 16; ++ii) xnvA[ii] = xnT[ii * BATCH + b];
#pragma unroll
    for (int ii = 0; ii < 4; ++ii) svA0[ii] = sr[ii];
#pragma unroll
    for (int jj = 0; jj < 4; ++jj) wvA0[jj] = wr[4 * jj + LU];

#pragma unroll 1
    for (int blk = 0; blk < K; blk += 160) {   // 2 phases/iter, A/B ping-pong
        const int nb1 = blk + 80;                              // always < K
        const int nb2 = (blk + 160 < K) ? (blk + 160) : 0;     // clamped: valid
        sse_phase<LU>(acc, xnvA, svA0, wvA0, svt, wvt, xnvB, svB0, wvB0,
                      xnT, wr, sr, b, blk, nb1);               // dead on last iter
        sse_phase<LU>(acc, xnvB, svB0, wvB0, svt, wvt, xnvA, svA0, wvA0,
                      xnT, wr, sr, b, nb1, nb2);
    }
    return acc;
}

template <int L, int IN, int OUT, bool FINAL>
__global__ __launch_bounds__(256, 6) void kan_layer(
    const float* __restrict__ w, const float* __restrict__ s,
    const float* __restrict__ bias, float* __restrict__ outf)
{
    const int o = blockIdx.x;
    const int tid = threadIdx.x;
    const int lane = tid & 63;
    // This wave's SSE lane (0..3); readfirstlane keeps it on the scalar path.
    const int lu = __builtin_amdgcn_readfirstlane(tid >> 6);
    const int b = blockIdx.y * 64 + lane;
    const float* __restrict__ xnT = xnT_ptr<L>();
    const float* __restrict__ wr = w + (size_t)o * IN * 5;
    const float* __restrict__ sr = s + (size_t)o * IN;

    float acc;
    switch (lu) {                                  // wave-uniform scalar branch
        case 0:  acc = sse_chain<IN, 0>(xnT, wr, sr, b); break;
        case 1:  acc = sse_chain<IN, 1>(xnT, wr, sr, b); break;
        case 2:  acc = sse_chain<IN, 2>(xnT, wr, sr, b); break;
        default: acc = sse_chain<IN, 3>(xnT, wr, sr, b); break;
    }

    // Combine the 4 SSE-lane chains with the exact npyv_sum_f32 hadd
    // pairings: (v0+v1)+(v2+v3).
    __shared__ float lds[4 * 64];
    lds[lu * 64 + lane] = acc;
    __syncthreads();
    if (tid < 64) {
        const float v0 = lds[tid];
        const float v1 = lds[64 + tid];
        const float v2 = lds[128 + tid];
        const float v3 = lds[192 + tid];
        float h = (v0 + v1) + (v2 + v3);
        h = h + bias[o];                           // b == 0, exact
        const int bb = blockIdx.y * 64 + tid;
        if constexpr (FINAL) {
            outf[bb * OUT + o] = tanh_f32_cr(h);
        } else {
            xnT_ptr<L + 1>()[o * BATCH + bb] = tanh_f32_cr(fmaxf(h, 0.0f));
        }
    }
}

extern "C" void kernel_launch(void* const* d_in, const int* in_sizes, int n_in,
                              void* d_out, int out_size, void* d_ws, size_t ws_size,
                              hipStream_t stream)
{
    const float* x  = (const float*)d_in[0];
    const float* w0 = (const float*)d_in[1];
    const float* s0 = (const float*)d_in[2];
    const float* b0 = (const float*)d_in[3];
    const float* w1 = (const float*)d_in[5];
    const float* s1 = (const float*)d_in[6];
    const float* b1 = (const float*)d_in[7];
    const float* w2 = (const float*)d_in[9];
    const float* s2 = (const float*)d_in[10];
    const float* b2 = (const float*)d_in[11];
    float* out = (float*)d_out;

    prep_tanhT<<<dim3(BATCH), dim3(D0), 0, stream>>>(x);

    // 256-thread blocks = 4 waves; wave = SSE lane, lane = batch element.
    kan_layer<0, D0, D1, false><<<dim3(D1, BATCH / 64), dim3(256), 0, stream>>>(w0, s0, b0, nullptr);
    kan_layer<1, D1, D2, false><<<dim3(D2, BATCH / 64), dim3(256), 0, stream>>>(w1, s1, b1, nullptr);
    kan_layer<2, D2, D3, true ><<<dim3(D3, BATCH / 64), dim3(256), 0, stream>>>(w2, s2, b2, out);
}

// Round 2
// 311.083 us; speedup vs baseline: 1.0327x; 1.0327x over previous
//
#include <hip/hip_runtime.h>
#include <math.h>

#define BATCH 256
#define D0 256
#define D1 512
#define D2 256
#define D3 128

// fp32 inter-layer activations — replicating numpy's fp32 pipeline.
__device__ float g_xnT0[D0 * BATCH];
__device__ float g_xnT1[D1 * BATCH];
__device__ float g_xnT2[D2 * BATCH];

template <int L> __device__ __forceinline__ float* xnT_ptr() {
    if constexpr (L == 0) return g_xnT0;
    else if constexpr (L == 1) return g_xnT1;
    else return g_xnT2;
}

__device__ __forceinline__ float tanh_f32_cr(float x) {
    return (float)tanh((double)x);
}

__global__ void prep_tanhT(const float* __restrict__ x) {
    int i = threadIdx.x;   // 0..255
    int b = blockIdx.x;    // 0..255
    g_xnT0[i * BATCH + b] = tanh_f32_cr(x[b * D0 + i]);
}

// Numerics (FROZEN — r17 proved it): per-term fp32 ops d=|xn-g|, m=d*s;
// RN32(exp(m)) via fp64 deg-8 Taylor + exact ldexpf (deg-7 flipped the bf16
// argmax by one quantum -> fail). Accumulation = numpy einsum baseline-SSE
// exactly: 4 lanes, unfused mul+add, reversed chain
// acc = p0+(p4+(p8+(p12+acc))), hadd tree (v0+v1)+(v2+v3). 1.95e-2 vs 2e-2.
//
// Falsification ledger: r14/r15 schedule pinning + LU-templating (WIN,
// banked); r16 2x occupancy (neutral — issue-bound); r17 cheaper exp (FAIL
// numerics); r7/r12 accumulation restructure (FAIL numerics); r20 VMEM
// prefetch helper (FAIL — scratch, WRITE 256KB->26MB); r22 pipelined helper
// with by-ref arrays (FAIL — scratch again at VGPR=40/cap84, WRITE
// 256KB->16.7MB, dur 115->122; address-taken array args defeat SROA).
// UNIT FIX (r22 postmortem): FETCH_SIZE is KB -> baseline HBM traffic is
// 5.3 MB/dispatch @49GB/s, i.e. memory is a non-issue; kernel is
// issue/stall-bound with VALUBusy ~85%.
//
// r23 (this round): same pipelining IDEA, spill-proof FORM. Double-buffer
// ONLY xnv[16] (the phase-top VMEM load whose wait is the suspected stall),
// expressed as a macro expanded in a single scope: no helper function, no
// by-ref arrays, no address-taken locals, all indices compile-time. s/w
// uniform s_loads stay exactly at the r21 position. FP op stream, operand
// values, and acc order are bit-identical to r21 -> numerics untouched by
// construction. launch_bounds(256,6) = spill insurance (cap 84 VGPR; r16
// proved 6 vs 8 waves/SIMD is perf-neutral).
// SENTINEL: WRITE_SIZE must stay 256/512KB. If this comes back clean but
// neutral, the xnv-latency hypothesis is dead and ~85% VALU is the
// structural ceiling of the frozen stream.

// One 80-term phase (20 terms for this wave's SSE lane LU).
// CUR: this phase's xnv (prefetched one phase ago). NXT: buffer filled here
// with the next phase's xnv (VMEM issued ~1 full phase before first use).
#define SSE_PHASE(CUR, NXT, BLK, NBLK)                                         \
  {                                                                            \
    const int ibase  = (BLK) / 5;                                              \
    const int nibase = (NBLK) / 5;                                             \
    float svv[16];                                                             \
    float wvv[20];                                                             \
    _Pragma("unroll")                                                          \
    for (int ii = 0; ii < 16; ++ii) svv[ii] = sr[ibase + ii];                  \
    _Pragma("unroll")                                                          \
    for (int jj = 0; jj < 20; ++jj) wvv[jj] = wr[(BLK) + 4 * jj + LU];         \
    _Pragma("unroll")                                                          \
    for (int ii = 0; ii < 16; ++ii)                                            \
        NXT[ii] = xnT[(nibase + ii) * BATCH + b];   /* coalesced VMEM */       \
    __builtin_amdgcn_sched_barrier(0);                                         \
    _Pragma("unroll")                                                          \
    for (int q = 0; q < 5; ++q) {              /* five 16-element SSE groups */\
        double uu[4], pp[4];                                                   \
        int ni[4];                                                             \
        _Pragma("unroll")                                                      \
        for (int j = 0; j < 4; ++j) {                                          \
            constexpr int Uq[4] = {0, 4, 8, 12};                               \
            const int U = q * 16 + Uq[j];      /* compile-time */              \
            const int c = U % 5;               /* compile-time */              \
            const int sum = c + LU;            /* compile-time */              \
            const int carry = (sum >= 5) ? 1 : 0;                              \
            const int idx = U / 5 + carry;     /* compile-time */              \
            const float gv = 0.5f * (float)(sum - 5 * carry) - 1.0f;           \
            const float d = fabsf(CUR[idx] - gv);       /* RN32 */             \
            const float m = -(d * svv[idx]);            /* RN32 */             \
            const double tt = (double)m * 1.4426950408889634;                  \
            const double nn = rint(tt);                                        \
            ni[j] = (int)nn;                                                   \
            uu[j] = (tt - nn) * 0.6931471805599453;                            \
        }                                                                      \
        __builtin_amdgcn_sched_barrier(0);                                     \
        _Pragma("unroll")                                                      \
        for (int j = 0; j < 4; ++j) pp[j] = fma(1.0 / 40320.0, uu[j], 1.0 / 5040.0); \
        __builtin_amdgcn_sched_barrier(0);                                     \
        _Pragma("unroll")                                                      \
        for (int j = 0; j < 4; ++j) pp[j] = fma(pp[j], uu[j], 1.0 / 720.0);    \
        __builtin_amdgcn_sched_barrier(0);                                     \
        _Pragma("unroll")                                                      \
        for (int j = 0; j < 4; ++j) pp[j] = fma(pp[j], uu[j], 1.0 / 120.0);    \
        __builtin_amdgcn_sched_barrier(0);                                     \
        _Pragma("unroll")                                                      \
        for (int j = 0; j < 4; ++j) pp[j] = fma(pp[j], uu[j], 1.0 / 24.0);     \
        __builtin_amdgcn_sched_barrier(0);                                     \
        _Pragma("unroll")                                                      \
        for (int j = 0; j < 4; ++j) pp[j] = fma(pp[j], uu[j], 1.0 / 6.0);      \
        __builtin_amdgcn_sched_barrier(0);                                     \
        _Pragma("unroll")                                                      \
        for (int j = 0; j < 4; ++j) pp[j] = fma(pp[j], uu[j], 0.5);            \
        __builtin_amdgcn_sched_barrier(0);                                     \
        _Pragma("unroll")                                                      \
        for (int j = 0; j < 4; ++j) pp[j] = fma(pp[j], uu[j], 1.0);            \
        __builtin_amdgcn_sched_barrier(0);                                     \
        _Pragma("unroll")                                                      \
        for (int j = 0; j < 4; ++j) pp[j] = fma(pp[j], uu[j], 1.0);            \
        __builtin_amdgcn_sched_barrier(0);                                     \
        float p[4];                                                            \
        _Pragma("unroll")                                                      \
        for (int j = 0; j < 4; ++j)                                            \
            p[j] = ldexpf((float)pp[j], ni[j]) * wvv[q * 4 + j];               \
        __builtin_amdgcn_sched_barrier(0);                                     \
        acc = p[3] + acc;                                                      \
        acc = p[2] + acc;                                                      \
        acc = p[1] + acc;                                                      \
        acc = p[0] + acc;                                                      \
    }                                                                          \
  }

template <int IN, int LU>
__device__ __forceinline__ float sse_chain(const float* __restrict__ xnT,
                                           const float* __restrict__ wr,
                                           const float* __restrict__ sr,
                                           const int b)
{
#pragma clang fp contract(off)
    constexpr int K = IN * 5;                  // 1280 or 2560: multiple of 160
    float acc = 0.f;
    float xA[16], xB[16];

    // ---- prologue: xnv for phase 0 ----
#pragma unroll
    for (int ii = 0; ii < 16; ++ii) xA[ii] = xnT[ii * BATCH + b];

#pragma unroll 1
    for (int blk = 0; blk < K; blk += 160) {   // 2 phases/iter, A/B ping-pong
        const int nb2 = (blk + 160 < K) ? (blk + 160) : 0;  // clamped: valid
        SSE_PHASE(xA, xB, blk, blk + 80)
        SSE_PHASE(xB, xA, blk + 80, nb2)       // last-iter prefetch is dead
    }
    return acc;
}

template <int L, int IN, int OUT, bool FINAL>
__global__ __launch_bounds__(256, 6) void kan_layer(
    const float* __restrict__ w, const float* __restrict__ s,
    const float* __restrict__ bias, float* __restrict__ outf)
{
    const int o = blockIdx.x;
    const int tid = threadIdx.x;
    const int lane = tid & 63;
    // This wave's SSE lane (0..3); readfirstlane keeps it on the scalar path.
    const int lu = __builtin_amdgcn_readfirstlane(tid >> 6);
    const int b = blockIdx.y * 64 + lane;
    const float* __restrict__ xnT = xnT_ptr<L>();
    const float* __restrict__ wr = w + (size_t)o * IN * 5;
    const float* __restrict__ sr = s + (size_t)o * IN;

    float acc;
    switch (lu) {                                  // wave-uniform scalar branch
        case 0:  acc = sse_chain<IN, 0>(xnT, wr, sr, b); break;
        case 1:  acc = sse_chain<IN, 1>(xnT, wr, sr, b); break;
        case 2:  acc = sse_chain<IN, 2>(xnT, wr, sr, b); break;
        default: acc = sse_chain<IN, 3>(xnT, wr, sr, b); break;
    }

    // Combine the 4 SSE-lane chains with the exact npyv_sum_f32 hadd
    // pairings: (v0+v1)+(v2+v3).
    __shared__ float lds[4 * 64];
    lds[lu * 64 + lane] = acc;
    __syncthreads();
    if (tid < 64) {
        const float v0 = lds[tid];
        const float v1 = lds[64 + tid];
        const float v2 = lds[128 + tid];
        const float v3 = lds[192 + tid];
        float h = (v0 + v1) + (v2 + v3);
        h = h + bias[o];                           // b == 0, exact
        const int bb = blockIdx.y * 64 + tid;
        if constexpr (FINAL) {
            outf[bb * OUT + o] = tanh_f32_cr(h);
        } else {
            xnT_ptr<L + 1>()[o * BATCH + bb] = tanh_f32_cr(fmaxf(h, 0.0f));
        }
    }
}

extern "C" void kernel_launch(void* const* d_in, const int* in_sizes, int n_in,
                              void* d_out, int out_size, void* d_ws, size_t ws_size,
                              hipStream_t stream)
{
    const float* x  = (const float*)d_in[0];
    const float* w0 = (const float*)d_in[1];
    const float* s0 = (const float*)d_in[2];
    const float* b0 = (const float*)d_in[3];
    const float* w1 = (const float*)d_in[5];
    const float* s1 = (const float*)d_in[6];
    const float* b1 = (const float*)d_in[7];
    const float* w2 = (const float*)d_in[9];
    const float* s2 = (const float*)d_in[10];
    const float* b2 = (const float*)d_in[11];
    float* out = (float*)d_out;

    prep_tanhT<<<dim3(BATCH), dim3(D0), 0, stream>>>(x);

    // 256-thread blocks = 4 waves; wave = SSE lane, lane = batch element.
    kan_layer<0, D0, D1, false><<<dim3(D1, BATCH / 64), dim3(256), 0, stream>>>(w0, s0, b0, nullptr);
    kan_layer<1, D1, D2, false><<<dim3(D2, BATCH / 64), dim3(256), 0, stream>>>(w1, s1, b1, nullptr);
    kan_layer<2, D2, D3, true ><<<dim3(D3, BATCH / 64), dim3(256), 0, stream>>>(w2, s2, b2, out);
}